// Round 8
// baseline (432.106 us; speedup 1.0000x reference)
//
#include <hip/hip_runtime.h>

#define N_NODES 100000
#define N_EDGES 1600000
#define HD 128
#define NH 4
#define NEG_SLOPE 0.2f

typedef __attribute__((ext_vector_type(8))) short short8v;
typedef __attribute__((ext_vector_type(4))) float float4v;
typedef __attribute__((ext_vector_type(2))) _Float16 half2v;

__device__ __forceinline__ unsigned short bf16_rne(float x) {
    unsigned u = __float_as_uint(x);
    unsigned r = u + 0x7fffu + ((u >> 16) & 1u);
    return (unsigned short)(r >> 16);
}
__device__ __forceinline__ float bf16_f(unsigned short h) {
    return __uint_as_float(((unsigned)h) << 16);
}

// ---------------------------------------------------------------------------
// One-shot W preprocessing (single block): wlr = W^T attn_{l,r} appended as a
// 9th column-tile; split-bf16 (hi/lo) B-fragments for 9 col-tiles x 4 k-tiles.
// ---------------------------------------------------------------------------
__global__ __launch_bounds__(256) void k_wsplit(const float* __restrict__ W,
                                                const float* __restrict__ attn_l,
                                                const float* __restrict__ attn_r,
                                                short* __restrict__ wfrag) {
    __shared__ float wlr[128][8];
    const int tid = threadIdx.x;
    for (int idx = tid; idx < 1024; idx += 256) {
        int c = idx >> 7, k = idx & 127;
        int head = c & 3;
        const float* av = (c < 4 ? attn_l : attn_r) + head * 32;
        const float* wp = W + head * 32 * HD + k;
        float s = 0.f;
        #pragma unroll
        for (int dd = 0; dd < 32; ++dd) s = fmaf(wp[dd * HD], av[dd], s);
        wlr[k][c] = s;
    }
    __syncthreads();
    const int wv = tid >> 6, lane = tid & 63;
    for (int t = wv; t < 36; t += 4) {
        int ct = t >> 2, kt = t & 3;
        int cIT = lane & 15;
        int k0 = kt * 32 + (lane >> 4) * 8;
        float wf[8];
        if (ct < 8) {
            int col = ct * 16 + cIT;
            const float4* wp = (const float4*)(W + col * HD + k0);
            float4 a = wp[0], b = wp[1];
            wf[0] = a.x; wf[1] = a.y; wf[2] = a.z; wf[3] = a.w;
            wf[4] = b.x; wf[5] = b.y; wf[6] = b.z; wf[7] = b.w;
        } else {
            #pragma unroll
            for (int j = 0; j < 8; ++j) wf[j] = (cIT < 8) ? wlr[k0 + j][cIT] : 0.f;
        }
        short* hi = wfrag + (size_t)((t * 2 + 0) * 64 + lane) * 8;
        short* lo = wfrag + (size_t)((t * 2 + 1) * 64 + lane) * 8;
        #pragma unroll
        for (int j = 0; j < 8; ++j) {
            unsigned short hh = bf16_rne(wf[j]);
            hi[j] = (short)hh;
            lo[j] = (short)bf16_rne(wf[j] - bf16_f(hh));
        }
    }
}

// ---------------------------------------------------------------------------
// Projection: h(f16) = feat @ W^T, el/er from appended 9th column-tile.
// Split-bf16 MFMA, no LDS/sync. Also zeroes counts[] (grid covers N_NODES).
// ---------------------------------------------------------------------------
__global__ __launch_bounds__(256) void k_proj(const float* __restrict__ feat,
                                              const short* __restrict__ wfrag,
                                              _Float16* __restrict__ hq,
                                              float* __restrict__ el,
                                              float* __restrict__ er,
                                              int* __restrict__ counts) {
    const int g = blockIdx.x * 256 + threadIdx.x;
    if (g < N_NODES) counts[g] = 0;

    const int wv = threadIdx.x >> 6, lane = threadIdx.x & 63;
    const int n0 = blockIdx.x * 64 + wv * 16;
    if (n0 + 16 > N_NODES) return;   // N_NODES % 16 == 0

    short8v ahi[4], alo[4];
    const int arow = n0 + (lane & 15);
    #pragma unroll
    for (int kt = 0; kt < 4; ++kt) {
        const float4* fp = (const float4*)(feat + (size_t)arow * HD + kt * 32 + (lane >> 4) * 8);
        float4 f0 = fp[0], f1 = fp[1];
        float ff[8] = {f0.x, f0.y, f0.z, f0.w, f1.x, f1.y, f1.z, f1.w};
        #pragma unroll
        for (int j = 0; j < 8; ++j) {
            unsigned short hh = bf16_rne(ff[j]);
            ahi[kt][j] = (short)hh;
            alo[kt][j] = (short)bf16_rne(ff[j] - bf16_f(hh));
        }
    }

    const short8v* wf = (const short8v*)wfrag;
    const int rbase = n0 + (lane >> 4) * 4;
    #pragma unroll
    for (int ct = 0; ct < 9; ++ct) {
        float4v acc = {0.f, 0.f, 0.f, 0.f};
        #pragma unroll
        for (int kt = 0; kt < 4; ++kt) {
            short8v bh = wf[((ct * 4 + kt) * 2 + 0) * 64 + lane];
            short8v bl = wf[((ct * 4 + kt) * 2 + 1) * 64 + lane];
            acc = __builtin_amdgcn_mfma_f32_16x16x32_bf16(ahi[kt], bh, acc, 0, 0, 0);
            acc = __builtin_amdgcn_mfma_f32_16x16x32_bf16(ahi[kt], bl, acc, 0, 0, 0);
            acc = __builtin_amdgcn_mfma_f32_16x16x32_bf16(alo[kt], bh, acc, 0, 0, 0);
        }
        if (ct < 8) {
            const int col = ct * 16 + (lane & 15);
            #pragma unroll
            for (int r = 0; r < 4; ++r)
                hq[(size_t)(rbase + r) * HD + col] = (_Float16)acc[r];
        } else {
            const int c = lane & 15;
            if (c < 4) {
                #pragma unroll
                for (int r = 0; r < 4; ++r) el[(rbase + r) * NH + c] = acc[r];
            } else if (c < 8) {
                #pragma unroll
                for (int r = 0; r < 4; ++r) er[(rbase + r) * NH + (c - 4)] = acc[r];
            }
        }
    }
}

// ---------------------------------------------------------------------------
// Degree histogram, 4 edges/thread (independent atomics pipeline 4-deep).
// Also zeroes the global segment cursor. N_EDGES % 4 == 0.
// ---------------------------------------------------------------------------
__global__ __launch_bounds__(256) void k_hist(const int* __restrict__ dst,
                                              int* __restrict__ counts,
                                              int* __restrict__ gtotal) {
    if (blockIdx.x == 0 && threadIdx.x == 0) *gtotal = 0;
    int e0 = (blockIdx.x * 256 + threadIdx.x) * 4;
    if (e0 >= N_EDGES) return;
    int4 d4 = *(const int4*)(dst + e0);
    atomicAdd(&counts[d4.x], 1);
    atomicAdd(&counts[d4.y], 1);
    atomicAdd(&counts[d4.z], 1);
    atomicAdd(&counts[d4.w], 1);
}

// ---------------------------------------------------------------------------
// Segment assignment: rowptr[i] = contiguous range of size counts[i], order
// arbitrary (wave-scan + one global atomicAdd per wave).
// ---------------------------------------------------------------------------
__global__ __launch_bounds__(256) void k_assign(const int* __restrict__ counts,
                                                int* __restrict__ rowptr,
                                                int* __restrict__ cursor,
                                                int* __restrict__ gtotal) {
    int i = blockIdx.x * 256 + threadIdx.x;
    int lane = threadIdx.x & 63;
    int c = (i < N_NODES) ? counts[i] : 0;
    int x = c;
    #pragma unroll
    for (int off = 1; off < 64; off <<= 1) {
        int y = __shfl_up(x, off);
        if (lane >= off) x += y;
    }
    int excl = x - c;
    int wtot = __shfl(x, 63);
    int base = 0;
    if (lane == 0) base = atomicAdd(gtotal, wtot);
    base = __shfl(base, 0);
    if (i < N_NODES) {
        rowptr[i] = base + excl;
        cursor[i] = base + excl;
    }
}

// ---------------------------------------------------------------------------
// Scatter, 4 edges/thread: 4 independent atomic+store chains per thread
// quadruple memory-level parallelism on the atomic->store latency chain.
// ---------------------------------------------------------------------------
__global__ __launch_bounds__(256) void k_scatter(const int* __restrict__ src,
                                                 const int* __restrict__ dst,
                                                 int* __restrict__ cursor,
                                                 int* __restrict__ ssrc) {
    int e0 = (blockIdx.x * 256 + threadIdx.x) * 4;
    if (e0 >= N_EDGES) return;   // N_EDGES % 4 == 0: full int4 always valid
    int4 d4 = *(const int4*)(dst + e0);
    int4 s4 = *(const int4*)(src + e0);
    int p0 = atomicAdd(&cursor[d4.x], 1);
    int p1 = atomicAdd(&cursor[d4.y], 1);
    int p2 = atomicAdd(&cursor[d4.z], 1);
    int p3 = atomicAdd(&cursor[d4.w], 1);
    ssrc[p0] = s4.x;
    ssrc[p1] = s4.y;
    ssrc[p2] = s4.z;
    ssrc[p3] = s4.w;
}

// ---------------------------------------------------------------------------
// Fused edge-softmax + aggregation, no max pass. One wave per dst node.
// Pass A: p=exp(lrelu(el[s]+er[d])), sum; cache p,s in LDS (deg<=128).
// Pass B (PV): 4-edge unroll, 4 independent accumulator chains.
// ---------------------------------------------------------------------------
__global__ __launch_bounds__(256) void k_agg2(const int* __restrict__ rowptr,
                                              const int* __restrict__ counts,
                                              const int* __restrict__ ssrc,
                                              const float* __restrict__ el,
                                              const float* __restrict__ er,
                                              const _Float16* __restrict__ hq,
                                              float* __restrict__ out) {
    __shared__ float4 sc[4][128];
    __shared__ int    sl[4][128];
    const int wv = threadIdx.x >> 6, lane = threadIdx.x & 63;
    const int d = blockIdx.x * 4 + wv;   // grid covers exactly N_NODES
    const int start = rowptr[d], deg = counts[d];
    const float4 erd = *(const float4*)(er + d * NH);
    const bool small = (deg <= 128);

    float4 sum = {0.f, 0.f, 0.f, 0.f};
    for (int j = lane; j < deg; j += 64) {
        int s = ssrc[start + j];
        float4 v = *(const float4*)(el + s * NH);
        v.x += erd.x; v.y += erd.y; v.z += erd.z; v.w += erd.w;
        v.x = v.x > 0.f ? v.x : NEG_SLOPE * v.x;
        v.y = v.y > 0.f ? v.y : NEG_SLOPE * v.y;
        v.z = v.z > 0.f ? v.z : NEG_SLOPE * v.z;
        v.w = v.w > 0.f ? v.w : NEG_SLOPE * v.w;
        v.x = __expf(v.x); v.y = __expf(v.y);
        v.z = __expf(v.z); v.w = __expf(v.w);
        if (small) { sc[wv][j] = v; sl[wv][j] = s; }
        sum.x += v.x; sum.y += v.y; sum.z += v.z; sum.w += v.w;
    }
    #pragma unroll
    for (int off = 32; off >= 1; off >>= 1) {
        sum.x += __shfl_xor(sum.x, off);
        sum.y += __shfl_xor(sum.y, off);
        sum.z += __shfl_xor(sum.z, off);
        sum.w += __shfl_xor(sum.w, off);
    }

    const int hsel = lane >> 4;   // head of feature pair (2*lane, 2*lane+1)
    const float sd = hsel == 0 ? sum.x : hsel == 1 ? sum.y : hsel == 2 ? sum.z : sum.w;
    const float rs = sd > 0.f ? 1.f / sd : 0.f;
    const float ec = hsel == 0 ? erd.x : hsel == 1 ? erd.y : hsel == 2 ? erd.z : erd.w;

    float ax0 = 0.f, ay0 = 0.f, ax1 = 0.f, ay1 = 0.f;
    float ax2 = 0.f, ay2 = 0.f, ax3 = 0.f, ay3 = 0.f;
    if (small) {
        int j = 0;
        for (; j + 3 < deg; j += 4) {
            int s0 = sl[wv][j], s1 = sl[wv][j + 1];
            int s2 = sl[wv][j + 2], s3 = sl[wv][j + 3];
            float p0 = ((const float*)&sc[wv][j])[hsel];
            float p1 = ((const float*)&sc[wv][j + 1])[hsel];
            float p2 = ((const float*)&sc[wv][j + 2])[hsel];
            float p3 = ((const float*)&sc[wv][j + 3])[hsel];
            half2v h0 = *(const half2v*)(hq + (size_t)s0 * HD + lane * 2);
            half2v h1 = *(const half2v*)(hq + (size_t)s1 * HD + lane * 2);
            half2v h2 = *(const half2v*)(hq + (size_t)s2 * HD + lane * 2);
            half2v h3 = *(const half2v*)(hq + (size_t)s3 * HD + lane * 2);
            ax0 = fmaf(p0, (float)h0.x, ax0); ay0 = fmaf(p0, (float)h0.y, ay0);
            ax1 = fmaf(p1, (float)h1.x, ax1); ay1 = fmaf(p1, (float)h1.y, ay1);
            ax2 = fmaf(p2, (float)h2.x, ax2); ay2 = fmaf(p2, (float)h2.y, ay2);
            ax3 = fmaf(p3, (float)h3.x, ax3); ay3 = fmaf(p3, (float)h3.y, ay3);
        }
        for (; j < deg; ++j) {
            int s0 = sl[wv][j];
            float p0 = ((const float*)&sc[wv][j])[hsel];
            half2v h0 = *(const half2v*)(hq + (size_t)s0 * HD + lane * 2);
            ax0 = fmaf(p0, (float)h0.x, ax0);
            ay0 = fmaf(p0, (float)h0.y, ay0);
        }
    } else {
        for (int j = 0; j < deg; ++j) {
            int s = ssrc[start + j];
            float v = el[s * NH + hsel] + ec;
            v = v > 0.f ? v : NEG_SLOPE * v;
            float p = __expf(v);
            half2v hv = *(const half2v*)(hq + (size_t)s * HD + lane * 2);
            ax0 = fmaf(p, (float)hv.x, ax0);
            ay0 = fmaf(p, (float)hv.y, ay0);
        }
    }
    float2 o;
    o.x = ((ax0 + ax1) + (ax2 + ax3)) * rs;
    o.y = ((ay0 + ay1) + (ay2 + ay3)) * rs;
    *(float2*)(out + (size_t)d * HD + lane * 2) = o;
}

extern "C" void kernel_launch(void* const* d_in, const int* in_sizes, int n_in,
                              void* d_out, int out_size, void* d_ws, size_t ws_size,
                              hipStream_t stream) {
    const float* feat   = (const float*)d_in[0];
    const int*   src    = (const int*)  d_in[1];
    const int*   dst    = (const int*)  d_in[2];
    const float* W      = (const float*)d_in[3];
    const float* attn_l = (const float*)d_in[4];
    const float* attn_r = (const float*)d_in[5];
    float* out = (float*)d_out;

    _Float16* hq = (_Float16*)d_ws;                      // N*128 halfs = 25.6 MB
    float* el    = (float*)(hq + (size_t)N_NODES * HD);  // N*4
    float* er    = el + (size_t)N_NODES * NH;            // N*4
    short* wfrag = (short*)(er + (size_t)N_NODES * NH);  // 36864 shorts
    int* counts  = (int*)(wfrag + 36864);
    int* rowptr  = counts + N_NODES;
    int* cursor  = rowptr + N_NODES;
    int* gtotal  = cursor + N_NODES;                     // 1 (padded to 64)
    int* ssrc    = gtotal + 64;                          // 1.6M

    const int EB = (N_EDGES / 4 + 255) / 256;            // 4-edge/thread grids
    k_wsplit <<<1, 256, 0, stream>>>(W, attn_l, attn_r, wfrag);
    k_proj   <<<(N_NODES + 63) / 64, 256, 0, stream>>>(feat, wfrag, hq, el, er, counts);
    k_hist   <<<EB, 256, 0, stream>>>(dst, counts, gtotal);
    k_assign <<<(N_NODES + 255) / 256, 256, 0, stream>>>(counts, rowptr, cursor, gtotal);
    k_scatter<<<EB, 256, 0, stream>>>(src, dst, cursor, ssrc);
    k_agg2   <<<N_NODES / 4, 256, 0, stream>>>(rowptr, counts, ssrc, el, er, hq, out);
}

// Round 11
// 338.322 us; speedup vs baseline: 1.2772x; 1.2772x over previous
//
#include <hip/hip_runtime.h>

#define N_NODES 100000
#define N_EDGES 1600000
#define HD 128
#define NH 4
#define NEG_SLOPE 0.2f
#define NREP 8   // counter replicas to cut same-address atomic serialization

typedef __attribute__((ext_vector_type(8))) short short8v;
typedef __attribute__((ext_vector_type(4))) float float4v;
typedef __attribute__((ext_vector_type(2))) _Float16 half2v;

__device__ __forceinline__ unsigned short bf16_rne(float x) {
    unsigned u = __float_as_uint(x);
    unsigned r = u + 0x7fffu + ((u >> 16) & 1u);
    return (unsigned short)(r >> 16);
}
__device__ __forceinline__ float bf16_f(unsigned short h) {
    return __uint_as_float(((unsigned)h) << 16);
}

// ---------------------------------------------------------------------------
// One-shot W preprocessing (single block): wlr = W^T attn_{l,r} appended as a
// 9th column-tile; split-bf16 (hi/lo) B-fragments for 9 col-tiles x 4 k-tiles.
// ---------------------------------------------------------------------------
__global__ __launch_bounds__(256) void k_wsplit(const float* __restrict__ W,
                                                const float* __restrict__ attn_l,
                                                const float* __restrict__ attn_r,
                                                short* __restrict__ wfrag) {
    __shared__ float wlr[128][8];
    const int tid = threadIdx.x;
    for (int idx = tid; idx < 1024; idx += 256) {
        int c = idx >> 7, k = idx & 127;
        int head = c & 3;
        const float* av = (c < 4 ? attn_l : attn_r) + head * 32;
        const float* wp = W + head * 32 * HD + k;
        float s = 0.f;
        #pragma unroll
        for (int dd = 0; dd < 32; ++dd) s = fmaf(wp[dd * HD], av[dd], s);
        wlr[k][c] = s;
    }
    __syncthreads();
    const int wv = tid >> 6, lane = tid & 63;
    for (int t = wv; t < 36; t += 4) {
        int ct = t >> 2, kt = t & 3;
        int cIT = lane & 15;
        int k0 = kt * 32 + (lane >> 4) * 8;
        float wf[8];
        if (ct < 8) {
            int col = ct * 16 + cIT;
            const float4* wp = (const float4*)(W + col * HD + k0);
            float4 a = wp[0], b = wp[1];
            wf[0] = a.x; wf[1] = a.y; wf[2] = a.z; wf[3] = a.w;
            wf[4] = b.x; wf[5] = b.y; wf[6] = b.z; wf[7] = b.w;
        } else {
            #pragma unroll
            for (int j = 0; j < 8; ++j) wf[j] = (cIT < 8) ? wlr[k0 + j][cIT] : 0.f;
        }
        short* hi = wfrag + (size_t)((t * 2 + 0) * 64 + lane) * 8;
        short* lo = wfrag + (size_t)((t * 2 + 1) * 64 + lane) * 8;
        #pragma unroll
        for (int j = 0; j < 8; ++j) {
            unsigned short hh = bf16_rne(wf[j]);
            hi[j] = (short)hh;
            lo[j] = (short)bf16_rne(wf[j] - bf16_f(hh));
        }
    }
}

// ---------------------------------------------------------------------------
// Projection: h(f16) = feat @ W^T, el/er from appended 9th column-tile.
// Split-bf16 MFMA, no LDS/sync. Also zeroes cnt[NREP][N] via grid-stride.
// ---------------------------------------------------------------------------
__global__ __launch_bounds__(256) void k_proj(const float* __restrict__ feat,
                                              const short* __restrict__ wfrag,
                                              _Float16* __restrict__ hq,
                                              float* __restrict__ el,
                                              float* __restrict__ er,
                                              int* __restrict__ cnt) {
    const int g = blockIdx.x * 256 + threadIdx.x;
    const int T = gridDim.x * 256;
    for (int i = g; i < NREP * N_NODES; i += T) cnt[i] = 0;

    const int wv = threadIdx.x >> 6, lane = threadIdx.x & 63;
    const int n0 = blockIdx.x * 64 + wv * 16;
    if (n0 + 16 > N_NODES) return;   // N_NODES % 16 == 0

    short8v ahi[4], alo[4];
    const int arow = n0 + (lane & 15);
    #pragma unroll
    for (int kt = 0; kt < 4; ++kt) {
        const float4* fp = (const float4*)(feat + (size_t)arow * HD + kt * 32 + (lane >> 4) * 8);
        float4 f0 = fp[0], f1 = fp[1];
        float ff[8] = {f0.x, f0.y, f0.z, f0.w, f1.x, f1.y, f1.z, f1.w};
        #pragma unroll
        for (int j = 0; j < 8; ++j) {
            unsigned short hh = bf16_rne(ff[j]);
            ahi[kt][j] = (short)hh;
            alo[kt][j] = (short)bf16_rne(ff[j] - bf16_f(hh));
        }
    }

    const short8v* wf = (const short8v*)wfrag;
    const int rbase = n0 + (lane >> 4) * 4;
    #pragma unroll
    for (int ct = 0; ct < 9; ++ct) {
        float4v acc = {0.f, 0.f, 0.f, 0.f};
        #pragma unroll
        for (int kt = 0; kt < 4; ++kt) {
            short8v bh = wf[((ct * 4 + kt) * 2 + 0) * 64 + lane];
            short8v bl = wf[((ct * 4 + kt) * 2 + 1) * 64 + lane];
            acc = __builtin_amdgcn_mfma_f32_16x16x32_bf16(ahi[kt], bh, acc, 0, 0, 0);
            acc = __builtin_amdgcn_mfma_f32_16x16x32_bf16(ahi[kt], bl, acc, 0, 0, 0);
            acc = __builtin_amdgcn_mfma_f32_16x16x32_bf16(alo[kt], bh, acc, 0, 0, 0);
        }
        if (ct < 8) {
            const int col = ct * 16 + (lane & 15);
            #pragma unroll
            for (int r = 0; r < 4; ++r)
                hq[(size_t)(rbase + r) * HD + col] = (_Float16)acc[r];
        } else {
            const int c = lane & 15;
            if (c < 4) {
                #pragma unroll
                for (int r = 0; r < 4; ++r) el[(rbase + r) * NH + c] = acc[r];
            } else if (c < 8) {
                #pragma unroll
                for (int r = 0; r < 4; ++r) er[(rbase + r) * NH + (c - 4)] = acc[r];
            }
        }
    }
}

// ---------------------------------------------------------------------------
// Histogram into NREP replica counters (rep = e & 7 -> ~2-way same-address
// collisions instead of 16) AND record each edge's within-(rep,node) rank.
// rank store is coalesced; gtotal zeroed here for k_assign.
// ---------------------------------------------------------------------------
__global__ __launch_bounds__(256) void k_hist(const int* __restrict__ dst,
                                              int* __restrict__ cnt,
                                              int* __restrict__ rank,
                                              int* __restrict__ gtotal) {
    if (blockIdx.x == 0 && threadIdx.x == 0) *gtotal = 0;
    int e = blockIdx.x * 256 + threadIdx.x;   // grid covers exactly N_EDGES
    int d = dst[e];
    int rep = e & (NREP - 1);
    rank[e] = atomicAdd(&cnt[rep * N_NODES + d], 1);
}

// ---------------------------------------------------------------------------
// Segment assignment. Per node: tot = sum_rep cnt[rep][d]; node segments get
// arbitrary-order contiguous ranges (wave-scan + one atomicAdd per wave);
// per-(rep,node) sub-segment bases = node base + prefix over rep.
// ---------------------------------------------------------------------------
__global__ __launch_bounds__(256) void k_assign(const int* __restrict__ cnt,
                                                int* __restrict__ rowptr,
                                                int* __restrict__ deg,
                                                int* __restrict__ pbase,
                                                int* __restrict__ gtotal) {
    int d = blockIdx.x * 256 + threadIdx.x;
    int lane = threadIdx.x & 63;
    int c[NREP];
    int tot = 0;
    if (d < N_NODES) {
        #pragma unroll
        for (int r = 0; r < NREP; ++r) { c[r] = cnt[r * N_NODES + d]; tot += c[r]; }
    }
    int x = tot;
    #pragma unroll
    for (int off = 1; off < 64; off <<= 1) {
        int y = __shfl_up(x, off);
        if (lane >= off) x += y;
    }
    int excl = x - tot;
    int wtot = __shfl(x, 63);
    int base = 0;
    if (lane == 0) base = atomicAdd(gtotal, wtot);
    base = __shfl(base, 0);
    if (d < N_NODES) {
        int nb = base + excl;
        rowptr[d] = nb;
        deg[d] = tot;
        #pragma unroll
        for (int r = 0; r < NREP; ++r) { pbase[r * N_NODES + d] = nb; nb += c[r]; }
    }
}

// ---------------------------------------------------------------------------
// Scatter: NO atomics. pos = pbase[rep][d] + rank[e]; fire-and-forget store.
// ---------------------------------------------------------------------------
__global__ __launch_bounds__(256) void k_scatter(const int* __restrict__ src,
                                                 const int* __restrict__ dst,
                                                 const int* __restrict__ rank,
                                                 const int* __restrict__ pbase,
                                                 int* __restrict__ ssrc) {
    int e = blockIdx.x * 256 + threadIdx.x;
    int d = dst[e];
    int rep = e & (NREP - 1);
    int pos = pbase[rep * N_NODES + d] + rank[e];
    ssrc[pos] = src[e];
}

// ---------------------------------------------------------------------------
// Fused edge-softmax + aggregation, no max pass. One wave per dst node.
// Pass A: p=exp(lrelu(el[s]+er[d])), sum; cache p,s in LDS (deg<=128).
// Pass B (PV): 4-edge unroll, 4 independent accumulator chains.
// ---------------------------------------------------------------------------
__global__ __launch_bounds__(256) void k_agg2(const int* __restrict__ rowptr,
                                              const int* __restrict__ deg_,
                                              const int* __restrict__ ssrc,
                                              const float* __restrict__ el,
                                              const float* __restrict__ er,
                                              const _Float16* __restrict__ hq,
                                              float* __restrict__ out) {
    __shared__ float4 sc[4][128];
    __shared__ int    sl[4][128];
    const int wv = threadIdx.x >> 6, lane = threadIdx.x & 63;
    const int d = blockIdx.x * 4 + wv;   // grid covers exactly N_NODES
    const int start = rowptr[d], deg = deg_[d];
    const float4 erd = *(const float4*)(er + d * NH);
    const bool small = (deg <= 128);

    float4 sum = {0.f, 0.f, 0.f, 0.f};
    for (int j = lane; j < deg; j += 64) {
        int s = ssrc[start + j];
        float4 v = *(const float4*)(el + s * NH);
        v.x += erd.x; v.y += erd.y; v.z += erd.z; v.w += erd.w;
        v.x = v.x > 0.f ? v.x : NEG_SLOPE * v.x;
        v.y = v.y > 0.f ? v.y : NEG_SLOPE * v.y;
        v.z = v.z > 0.f ? v.z : NEG_SLOPE * v.z;
        v.w = v.w > 0.f ? v.w : NEG_SLOPE * v.w;
        v.x = __expf(v.x); v.y = __expf(v.y);
        v.z = __expf(v.z); v.w = __expf(v.w);
        if (small) { sc[wv][j] = v; sl[wv][j] = s; }
        sum.x += v.x; sum.y += v.y; sum.z += v.z; sum.w += v.w;
    }
    #pragma unroll
    for (int off = 32; off >= 1; off >>= 1) {
        sum.x += __shfl_xor(sum.x, off);
        sum.y += __shfl_xor(sum.y, off);
        sum.z += __shfl_xor(sum.z, off);
        sum.w += __shfl_xor(sum.w, off);
    }

    const int hsel = lane >> 4;   // head of feature pair (2*lane, 2*lane+1)
    const float sd = hsel == 0 ? sum.x : hsel == 1 ? sum.y : hsel == 2 ? sum.z : sum.w;
    const float rs = sd > 0.f ? 1.f / sd : 0.f;
    const float ec = hsel == 0 ? erd.x : hsel == 1 ? erd.y : hsel == 2 ? erd.z : erd.w;

    float ax0 = 0.f, ay0 = 0.f, ax1 = 0.f, ay1 = 0.f;
    float ax2 = 0.f, ay2 = 0.f, ax3 = 0.f, ay3 = 0.f;
    if (small) {
        int j = 0;
        for (; j + 3 < deg; j += 4) {
            int s0 = sl[wv][j], s1 = sl[wv][j + 1];
            int s2 = sl[wv][j + 2], s3 = sl[wv][j + 3];
            float p0 = ((const float*)&sc[wv][j])[hsel];
            float p1 = ((const float*)&sc[wv][j + 1])[hsel];
            float p2 = ((const float*)&sc[wv][j + 2])[hsel];
            float p3 = ((const float*)&sc[wv][j + 3])[hsel];
            half2v h0 = *(const half2v*)(hq + (size_t)s0 * HD + lane * 2);
            half2v h1 = *(const half2v*)(hq + (size_t)s1 * HD + lane * 2);
            half2v h2 = *(const half2v*)(hq + (size_t)s2 * HD + lane * 2);
            half2v h3 = *(const half2v*)(hq + (size_t)s3 * HD + lane * 2);
            ax0 = fmaf(p0, (float)h0.x, ax0); ay0 = fmaf(p0, (float)h0.y, ay0);
            ax1 = fmaf(p1, (float)h1.x, ax1); ay1 = fmaf(p1, (float)h1.y, ay1);
            ax2 = fmaf(p2, (float)h2.x, ax2); ay2 = fmaf(p2, (float)h2.y, ay2);
            ax3 = fmaf(p3, (float)h3.x, ax3); ay3 = fmaf(p3, (float)h3.y, ay3);
        }
        for (; j < deg; ++j) {
            int s0 = sl[wv][j];
            float p0 = ((const float*)&sc[wv][j])[hsel];
            half2v h0 = *(const half2v*)(hq + (size_t)s0 * HD + lane * 2);
            ax0 = fmaf(p0, (float)h0.x, ax0);
            ay0 = fmaf(p0, (float)h0.y, ay0);
        }
    } else {
        for (int j = 0; j < deg; ++j) {
            int s = ssrc[start + j];
            float v = el[s * NH + hsel] + ec;
            v = v > 0.f ? v : NEG_SLOPE * v;
            float p = __expf(v);
            half2v hv = *(const half2v*)(hq + (size_t)s * HD + lane * 2);
            ax0 = fmaf(p, (float)hv.x, ax0);
            ay0 = fmaf(p, (float)hv.y, ay0);
        }
    }
    float2 o;
    o.x = ((ax0 + ax1) + (ax2 + ax3)) * rs;
    o.y = ((ay0 + ay1) + (ay2 + ay3)) * rs;
    *(float2*)(out + (size_t)d * HD + lane * 2) = o;
}

extern "C" void kernel_launch(void* const* d_in, const int* in_sizes, int n_in,
                              void* d_out, int out_size, void* d_ws, size_t ws_size,
                              hipStream_t stream) {
    const float* feat   = (const float*)d_in[0];
    const int*   src    = (const int*)  d_in[1];
    const int*   dst    = (const int*)  d_in[2];
    const float* W      = (const float*)d_in[3];
    const float* attn_l = (const float*)d_in[4];
    const float* attn_r = (const float*)d_in[5];
    float* out = (float*)d_out;

    _Float16* hq = (_Float16*)d_ws;                      // N*128 halfs = 25.6 MB
    float* el    = (float*)(hq + (size_t)N_NODES * HD);  // N*4
    float* er    = el + (size_t)N_NODES * NH;            // N*4
    short* wfrag = (short*)(er + (size_t)N_NODES * NH);  // 36864 shorts
    int* cnt     = (int*)(wfrag + 36864);                // NREP*N
    int* pbase   = cnt + NREP * N_NODES;                 // NREP*N
    int* rowptr  = pbase + NREP * N_NODES;               // N
    int* deg     = rowptr + N_NODES;                     // N
    int* gtotal  = deg + N_NODES;                        // 1 (padded to 64)
    int* rank    = gtotal + 64;                          // E
    int* ssrc    = rank + N_EDGES;                       // E

    k_wsplit <<<1, 256, 0, stream>>>(W, attn_l, attn_r, wfrag);
    k_proj   <<<(N_NODES + 63) / 64, 256, 0, stream>>>(feat, wfrag, hq, el, er, cnt);
    k_hist   <<<N_EDGES / 256, 256, 0, stream>>>(dst, cnt, rank, gtotal);
    k_assign <<<(N_NODES + 255) / 256, 256, 0, stream>>>(cnt, rowptr, deg, pbase, gtotal);
    k_scatter<<<N_EDGES / 256, 256, 0, stream>>>(src, dst, rank, pbase, ssrc);
    k_agg2   <<<N_NODES / 4, 256, 0, stream>>>(rowptr, deg, ssrc, el, er, hq, out);
}